// Round 9
// baseline (8467.438 us; speedup 1.0000x reference)
//
#include <hip/hip_runtime.h>
#include <hip/hip_bf16.h>
#include <math.h>

#define B_ 128
#define S_ 1024
#define H_ 512
#define E_ 512
#define T_ 64
#define L_ 128
#define G4H 2048  // 4*H
#define QS 8      // attention s-splits

typedef __attribute__((ext_vector_type(8))) short bf16x8;
typedef __attribute__((ext_vector_type(4))) float f32x4;

__device__ inline float sigmoidf_(float x) { return 1.f / (1.f + expf(-x)); }
__device__ inline float fast_tanhf_(float x) {
    float e = __expf(2.f * x);
    return 1.f - 2.f / (e + 1.f);
}
__device__ inline unsigned f2bf1(float f) {
    unsigned u = __float_as_uint(f);
    return (u + 0x7fffu + ((u >> 16) & 1u)) >> 16;
}

// ---------------------------------------------------------------------------
// fp32-accurate GEMM via bf16 split MFMA (Markidis 3-product), validated R4-R6.
// ---------------------------------------------------------------------------
#define LDP 40
__global__ __launch_bounds__(256) void gemm_split(
    const float* __restrict__ A, int lda,
    const float* __restrict__ W, int ldw,
    const float* __restrict__ bias,
    const float* __restrict__ Cinit, int ldci,
    float* __restrict__ C, int ldc,
    int K, int act, int perm)
{
    __shared__ unsigned short Ah[128 * LDP];
    __shared__ unsigned short Al[128 * LDP];
    __shared__ unsigned short Bh[128 * LDP];
    __shared__ unsigned short Bl[128 * LDP];
    const int n0 = blockIdx.x * 128;
    const int m0 = blockIdx.y * 128;
    const int t = threadIdx.x;
    const int lane = t & 63, wv = t >> 6;
    const int wr = wv >> 1, wc = wv & 1;
    const int row = t >> 1, koff = (t & 1) * 16;

    f32x4 acc[4][4] = {};

    float av[16], wvv[16];
    {
        const float* ap = A + (size_t)(m0 + row) * lda + koff;
        const float* wp = W + (size_t)(n0 + row) * ldw + koff;
#pragma unroll
        for (int q = 0; q < 4; ++q) {
            *reinterpret_cast<float4*>(&av[q * 4]) = *reinterpret_cast<const float4*>(ap + q * 4);
            *reinterpret_cast<float4*>(&wvv[q * 4]) = *reinterpret_cast<const float4*>(wp + q * 4);
        }
    }

    for (int kt = 0; kt < K; kt += 32) {
        unsigned short ah[16], al[16], bh[16], bl[16];
#pragma unroll
        for (int e = 0; e < 16; ++e) {
            unsigned ha = f2bf1(av[e]);
            float hf = __uint_as_float(ha << 16);
            ah[e] = (unsigned short)ha;
            al[e] = (unsigned short)f2bf1(av[e] - hf);
            unsigned hw = f2bf1(wvv[e]);
            float hwf = __uint_as_float(hw << 16);
            bh[e] = (unsigned short)hw;
            bl[e] = (unsigned short)f2bf1(wvv[e] - hwf);
        }
        __syncthreads();
        *reinterpret_cast<uint4*>(&Ah[row * LDP + koff])     = *reinterpret_cast<uint4*>(&ah[0]);
        *reinterpret_cast<uint4*>(&Ah[row * LDP + koff + 8]) = *reinterpret_cast<uint4*>(&ah[8]);
        *reinterpret_cast<uint4*>(&Al[row * LDP + koff])     = *reinterpret_cast<uint4*>(&al[0]);
        *reinterpret_cast<uint4*>(&Al[row * LDP + koff + 8]) = *reinterpret_cast<uint4*>(&al[8]);
        *reinterpret_cast<uint4*>(&Bh[row * LDP + koff])     = *reinterpret_cast<uint4*>(&bh[0]);
        *reinterpret_cast<uint4*>(&Bh[row * LDP + koff + 8]) = *reinterpret_cast<uint4*>(&bh[8]);
        *reinterpret_cast<uint4*>(&Bl[row * LDP + koff])     = *reinterpret_cast<uint4*>(&bl[0]);
        *reinterpret_cast<uint4*>(&Bl[row * LDP + koff + 8]) = *reinterpret_cast<uint4*>(&bl[8]);
        __syncthreads();

        if (kt + 32 < K) {
            const float* ap = A + (size_t)(m0 + row) * lda + kt + 32 + koff;
            const float* wp = W + (size_t)(n0 + row) * ldw + kt + 32 + koff;
#pragma unroll
            for (int q = 0; q < 4; ++q) {
                *reinterpret_cast<float4*>(&av[q * 4]) = *reinterpret_cast<const float4*>(ap + q * 4);
                *reinterpret_cast<float4*>(&wvv[q * 4]) = *reinterpret_cast<const float4*>(wp + q * 4);
            }
        }

        bf16x8 fah[4], fal[4], fbh[4], fbl[4];
        const int kq = (lane >> 4) * 8;
#pragma unroll
        for (int i = 0; i < 4; ++i) {
            const int ar = wr * 64 + i * 16 + (lane & 15);
            const int br = wc * 64 + i * 16 + (lane & 15);
            fah[i] = *reinterpret_cast<const bf16x8*>(&Ah[ar * LDP + kq]);
            fal[i] = *reinterpret_cast<const bf16x8*>(&Al[ar * LDP + kq]);
            fbh[i] = *reinterpret_cast<const bf16x8*>(&Bh[br * LDP + kq]);
            fbl[i] = *reinterpret_cast<const bf16x8*>(&Bl[br * LDP + kq]);
        }
#pragma unroll
        for (int i = 0; i < 4; ++i)
#pragma unroll
            for (int j = 0; j < 4; ++j) {
                acc[i][j] = __builtin_amdgcn_mfma_f32_16x16x32_bf16(fah[i], fbh[j], acc[i][j], 0, 0, 0);
                acc[i][j] = __builtin_amdgcn_mfma_f32_16x16x32_bf16(fal[i], fbh[j], acc[i][j], 0, 0, 0);
                acc[i][j] = __builtin_amdgcn_mfma_f32_16x16x32_bf16(fah[i], fbl[j], acc[i][j], 0, 0, 0);
            }
    }

#pragma unroll
    for (int i = 0; i < 4; ++i)
#pragma unroll
        for (int j = 0; j < 4; ++j) {
            const int n = n0 + wc * 64 + j * 16 + (lane & 15);
            const float bs = bias ? bias[n] : 0.f;
#pragma unroll
            for (int r = 0; r < 4; ++r) {
                const int m = m0 + wr * 64 + i * 16 + (lane >> 4) * 4 + r;
                float v = acc[i][j][r] + bs;
                if (Cinit) v += Cinit[(size_t)m * ldci + n];
                if (act == 1) v = tanhf(v);
                size_t crow;
                if (perm) { int bb = m & 127, tt = m >> 7; crow = ((size_t)bb * T_ + tt) * ldc; }
                else crow = (size_t)m * ldc;
                C[crow + n] = v;
            }
        }
}

// ---------------------------------------------------------------------------
// Permute LSTM weights: row r' = 4h+g  <-  row g*512+h
// ---------------------------------------------------------------------------
__global__ __launch_bounds__(128) void k_perm(
    const float* __restrict__ W_ih, const float* __restrict__ W_hh,
    const float* __restrict__ b_ih, const float* __restrict__ b_hh,
    float* __restrict__ Wip, float* __restrict__ Whp, float* __restrict__ bp)
{
    int rp = blockIdx.x;
    int h = rp >> 2, g = rp & 3;
    int src = g * 512 + h;
    int t = threadIdx.x;
    const float4* si = reinterpret_cast<const float4*>(W_ih + (size_t)src * 512);
    const float4* sh = reinterpret_cast<const float4*>(W_hh + (size_t)src * 512);
    float4* di = reinterpret_cast<float4*>(Wip + (size_t)rp * 512);
    float4* dh = reinterpret_cast<float4*>(Whp + (size_t)rp * 512);
    di[t] = si[t];
    dh[t] = sh[t];
    if (t == 0) bp[rp] = b_ih[src] + b_hh[src];
}

// ---------------------------------------------------------------------------
// Fused gates GEMM (permuted) + LSTM pointwise.  fused=1: A-staging computes
// h(t-1) = tanh(b_ho + sum Po) on the fly and (blockIdx.x==0) writes hist.
// ---------------------------------------------------------------------------
__global__ __launch_bounds__(256) void k_gateslstm(
    const float* __restrict__ hbuf,
    const float* __restrict__ Po,
    const float* __restrict__ b_ho,
    const float* __restrict__ Whp,
    const float* __restrict__ xproj_t,
    float* __restrict__ cbuf,
    float* __restrict__ hlstm,
    float* __restrict__ hist_prev,
    int fused)
{
    __shared__ float As[16][32];
    __shared__ float Ws[16][64];
    const int n0 = blockIdx.x * 64;
    const int m0 = blockIdx.y * 32;
    const int t = threadIdx.x;
    const int tx = t & 15;
    const int ty = t >> 4;
    const int alr = t >> 3, alk = (t & 7) * 2;
    const int wlr = t >> 2, wlk = (t & 3) * 4;

    float acc[2][4] = {};

    auto load_pa = [&](int k0) -> float2 {
        const int row = m0 + alr, k = k0 + alk;
        if (!fused) return *reinterpret_cast<const float2*>(hbuf + (size_t)row * 512 + k);
        float s0 = b_ho[k], s1 = b_ho[k + 1];
#pragma unroll
        for (int ks = 0; ks < 8; ++ks) {
            float2 p = *reinterpret_cast<const float2*>(Po + ((size_t)ks * 128 + row) * 512 + k);
            s0 += p.x; s1 += p.y;
        }
        float2 r; r.x = tanhf(s0); r.y = tanhf(s1);
        if (blockIdx.x == 0)
            *reinterpret_cast<float2*>(hist_prev + (size_t)row * 1024 + k) = r;
        return r;
    };

    float2 pa = load_pa(0);
    float4 pv = *reinterpret_cast<const float4*>(Whp + (size_t)(n0 + wlr) * 512 + wlk);

    for (int k0 = 0; k0 < 512; k0 += 16) {
        __syncthreads();
        As[alk + 0][alr] = pa.x; As[alk + 1][alr] = pa.y;
        Ws[wlk + 0][wlr] = pv.x; Ws[wlk + 1][wlr] = pv.y;
        Ws[wlk + 2][wlr] = pv.z; Ws[wlk + 3][wlr] = pv.w;
        __syncthreads();
        if (k0 + 16 < 512) {
            pa = load_pa(k0 + 16);
            pv = *reinterpret_cast<const float4*>(Whp + (size_t)(n0 + wlr) * 512 + k0 + 16 + wlk);
        }
#pragma unroll
        for (int kk = 0; kk < 16; ++kk) {
            float a[2], b[4];
            a[0] = As[kk][ty * 2]; a[1] = As[kk][ty * 2 + 1];
#pragma unroll
            for (int j = 0; j < 4; ++j) b[j] = Ws[kk][tx * 4 + j];
#pragma unroll
            for (int i = 0; i < 2; ++i)
#pragma unroll
                for (int j = 0; j < 4; ++j) acc[i][j] = fmaf(a[i], b[j], acc[i][j]);
        }
    }

    const int h = (n0 >> 2) + tx;
#pragma unroll
    for (int i = 0; i < 2; ++i) {
        const int b = m0 + ty * 2 + i;
        float4 xp = *reinterpret_cast<const float4*>(xproj_t + (size_t)b * G4H + n0 + tx * 4);
        float ig = sigmoidf_(acc[i][0] + xp.x);
        float fg = sigmoidf_(acc[i][1] + xp.y);
        float gg = tanhf(acc[i][2] + xp.z);
        float og = sigmoidf_(acc[i][3] + xp.w);
        float c = fg * cbuf[(size_t)b * 512 + h] + ig * gg;
        cbuf[(size_t)b * 512 + h] = c;
        hlstm[(size_t)b * 512 + h] = og * tanhf(c);
    }
}

// ---------------------------------------------------------------------------
// Small-M split-K GEMM, register-prefetched.
// ---------------------------------------------------------------------------
__global__ __launch_bounds__(256) void gemm_stepk(
    const float* __restrict__ A, int lda,
    const float* __restrict__ W, int ldw,
    float* __restrict__ P, int N, int Kc)
{
    __shared__ float As[16][128];
    __shared__ float Ws[16][64];
    const int n0 = blockIdx.x * 64;
    const int k0 = blockIdx.y * Kc;
    const int t = threadIdx.x;
    const int tx = t & 15;
    const int ty = t >> 4;
    const int ar = t >> 1, akq = (t & 1) * 8;
    const int wr = t >> 2, wkq = (t & 3) * 4;

    float acc[8][4] = {};

    float4 a0 = *reinterpret_cast<const float4*>(A + (size_t)ar * lda + k0 + akq);
    float4 a1 = *reinterpret_cast<const float4*>(A + (size_t)ar * lda + k0 + akq + 4);
    float4 w0 = *reinterpret_cast<const float4*>(W + (size_t)(n0 + wr) * ldw + k0 + wkq);

    for (int kb = 0; kb < Kc; kb += 16) {
        __syncthreads();
        As[akq + 0][ar] = a0.x; As[akq + 1][ar] = a0.y; As[akq + 2][ar] = a0.z; As[akq + 3][ar] = a0.w;
        As[akq + 4][ar] = a1.x; As[akq + 5][ar] = a1.y; As[akq + 6][ar] = a1.z; As[akq + 7][ar] = a1.w;
        Ws[wkq + 0][wr] = w0.x; Ws[wkq + 1][wr] = w0.y; Ws[wkq + 2][wr] = w0.z; Ws[wkq + 3][wr] = w0.w;
        __syncthreads();
        if (kb + 16 < Kc) {
            a0 = *reinterpret_cast<const float4*>(A + (size_t)ar * lda + k0 + kb + 16 + akq);
            a1 = *reinterpret_cast<const float4*>(A + (size_t)ar * lda + k0 + kb + 16 + akq + 4);
            w0 = *reinterpret_cast<const float4*>(W + (size_t)(n0 + wr) * ldw + k0 + kb + 16 + wkq);
        }
#pragma unroll
        for (int kk = 0; kk < 16; ++kk) {
            float a[8], b[4];
#pragma unroll
            for (int i = 0; i < 8; ++i) a[i] = As[kk][ty * 8 + i];
#pragma unroll
            for (int j = 0; j < 4; ++j) b[j] = Ws[kk][tx * 4 + j];
#pragma unroll
            for (int i = 0; i < 8; ++i)
#pragma unroll
                for (int j = 0; j < 4; ++j) acc[i][j] = fmaf(a[i], b[j], acc[i][j]);
        }
    }

#pragma unroll
    for (int i = 0; i < 8; ++i) {
        const int m = ty * 8 + i;
#pragma unroll
        for (int j = 0; j < 4; ++j)
            P[((size_t)blockIdx.y * 128 + m) * N + n0 + tx * 4 + j] = acc[i][j];
    }
}

// ---------------------------------------------------------------------------
// W_ho GEMM with fused softmax-merge A-staging (Q=8), register-prefetched.
// ---------------------------------------------------------------------------
__global__ __launch_bounds__(256) void k_who(
    const float* __restrict__ pm, const float* __restrict__ pl,
    const float* __restrict__ pw, const float* __restrict__ hlstm,
    const float* __restrict__ W_ho,
    float* __restrict__ P, float* __restrict__ hist_t)
{
    __shared__ float As[16][128];
    __shared__ float Ws[16][64];
    __shared__ float eql[128][QS];
    const int n0 = blockIdx.x * 64;
    const int k0 = blockIdx.y * 128;
    const int t = threadIdx.x;
    const int tx = t & 15;
    const int ty = t >> 4;
    const int ar = t >> 1, akq = (t & 1) * 8;
    const int wr = t >> 2, wkq = (t & 3) * 4;
    const bool merge_side = (k0 < 512);
    const bool writer = (blockIdx.x == 0) && merge_side;

    if (merge_side && t < 128) {
        float mq[QS], eq[QS];
        float M = -INFINITY;
#pragma unroll
        for (int q = 0; q < QS; ++q) { mq[q] = pm[QS * t + q]; M = fmaxf(M, mq[q]); }
        float Lt = 0.f;
#pragma unroll
        for (int q = 0; q < QS; ++q) { eq[q] = __expf(mq[q] - M); Lt += eq[q] * pl[QS * t + q]; }
        float inv = 1.f / Lt;
#pragma unroll
        for (int q = 0; q < QS; ++q) eql[t][q] = eq[q] * inv;
    }
    __syncthreads();

    float acc[8][4] = {};
    float av[8];
    float4 w0;

    auto load_stage = [&](int kb) {
        const int kg = k0 + kb + akq;
        if (merge_side) {
#pragma unroll
            for (int e = 0; e < 8; ++e) av[e] = 0.f;
#pragma unroll
            for (int q = 0; q < QS; ++q) {
                const float* pr = pw + (size_t)(QS * ar + q) * 512 + kg;
                float4 pa = *reinterpret_cast<const float4*>(pr);
                float4 pb = *reinterpret_cast<const float4*>(pr + 4);
                float qw = eql[ar][q];
                av[0] = fmaf(qw, pa.x, av[0]); av[1] = fmaf(qw, pa.y, av[1]);
                av[2] = fmaf(qw, pa.z, av[2]); av[3] = fmaf(qw, pa.w, av[3]);
                av[4] = fmaf(qw, pb.x, av[4]); av[5] = fmaf(qw, pb.y, av[5]);
                av[6] = fmaf(qw, pb.z, av[6]); av[7] = fmaf(qw, pb.w, av[7]);
            }
            if (writer) {
                *reinterpret_cast<float4*>(hist_t + (size_t)ar * 1024 + 512 + kg) = *reinterpret_cast<float4*>(&av[0]);
                *reinterpret_cast<float4*>(hist_t + (size_t)ar * 1024 + 512 + kg + 4) = *reinterpret_cast<float4*>(&av[4]);
            }
        } else {
            *reinterpret_cast<float4*>(&av[0]) = *reinterpret_cast<const float4*>(hlstm + (size_t)ar * 512 + kg - 512);
            *reinterpret_cast<float4*>(&av[4]) = *reinterpret_cast<const float4*>(hlstm + (size_t)ar * 512 + kg - 512 + 4);
        }
        w0 = *reinterpret_cast<const float4*>(W_ho + (size_t)(n0 + wr) * 1024 + k0 + kb + wkq);
    };

    load_stage(0);

    for (int kb = 0; kb < 128; kb += 16) {
        __syncthreads();
        As[akq + 0][ar] = av[0]; As[akq + 1][ar] = av[1]; As[akq + 2][ar] = av[2]; As[akq + 3][ar] = av[3];
        As[akq + 4][ar] = av[4]; As[akq + 5][ar] = av[5]; As[akq + 6][ar] = av[6]; As[akq + 7][ar] = av[7];
        Ws[wkq + 0][wr] = w0.x; Ws[wkq + 1][wr] = w0.y; Ws[wkq + 2][wr] = w0.z; Ws[wkq + 3][wr] = w0.w;
        __syncthreads();
        if (kb + 16 < 128) load_stage(kb + 16);
#pragma unroll
        for (int kk = 0; kk < 16; ++kk) {
            float a[8], b[4];
#pragma unroll
            for (int i = 0; i < 8; ++i) a[i] = As[kk][ty * 8 + i];
#pragma unroll
            for (int j = 0; j < 4; ++j) b[j] = Ws[kk][tx * 4 + j];
#pragma unroll
            for (int i = 0; i < 8; ++i)
#pragma unroll
                for (int j = 0; j < 4; ++j) acc[i][j] = fmaf(a[i], b[j], acc[i][j]);
        }
    }

#pragma unroll
    for (int i = 0; i < 8; ++i) {
        const int m = ty * 8 + i;
#pragma unroll
        for (int j = 0; j < 4; ++j)
            P[((size_t)blockIdx.y * 128 + m) * 512 + n0 + tx * 4 + j] = acc[i][j];
    }
}

// ---------------------------------------------------------------------------
__global__ void k_embed(const float* __restrict__ dec_in, const int* __restrict__ labels,
                        const float* __restrict__ emb, float* __restrict__ X)
{
    size_t total = (size_t)T_ * B_ * E_;
    for (size_t i = (size_t)blockIdx.x * blockDim.x + threadIdx.x; i < total;
         i += (size_t)gridDim.x * blockDim.x) {
        int e = (int)(i % E_);
        int b = (int)((i / E_) % B_);
        int t = (int)(i / ((size_t)E_ * B_));
        float v;
        if (t == 0) v = dec_in[b * E_ + e];
        else {
            int lab = labels[b * T_ + (t - 1)];
            v = emb[(size_t)lab * E_ + e];
        }
        X[i] = v;
    }
}

__global__ void k_init(const float* __restrict__ h0, const float* __restrict__ c0,
                       float* __restrict__ hbuf, float* __restrict__ cbuf)
{
    int i = blockIdx.x * blockDim.x + threadIdx.x;
    hbuf[i] = h0[i];
    cbuf[i] = c0[i];
}

// ---------------------------------------------------------------------------
// Attention (fp32 ctx): block (b, q of QS=8) handles 128 s-values.
// 8 waves x 16 s, 2-row prefetch; online softmax; partials (m,l,w[512]).
// Prologue sums the 8 W_attn_in split-K partials.
// ---------------------------------------------------------------------------
__global__ __launch_bounds__(512) void k_attn(const float* __restrict__ ctx,
    const float* __restrict__ Pa, const float* __restrict__ b_ain,
    const float* __restrict__ Vv,
    float* __restrict__ pm, float* __restrict__ pl, float* __restrict__ pw)
{
    int blk = blockIdx.x;
    int b = blk >> 3, q = blk & 7;
    int tid = threadIdx.x, lane = tid & 63, wv = tid >> 6;

    __shared__ float inp_sh[512];
    {
        float s = b_ain[tid];
#pragma unroll
        for (int ks = 0; ks < 8; ++ks) s += Pa[((size_t)ks * 128 + b) * 512 + tid];
        inp_sh[tid] = s;
    }
    __syncthreads();

    float inpr[8], vr[8];
    {
        const float4* v4 = reinterpret_cast<const float4*>(Vv) + lane * 2;
        *(float4*)&vr[0] = v4[0];   *(float4*)&vr[4] = v4[1];
#pragma unroll
        for (int k = 0; k < 8; ++k) inpr[k] = inp_sh[lane * 8 + k];
    }
    const float* sp = ctx + ((size_t)b * S_ + q * 128 + wv * 16) * H_ + lane * 8;

    float m = -INFINITY, l = 0.f, w[8] = {};

    auto process = [&](float4 u0, float4 u1) {
        float c8[8];
        *(float4*)&c8[0] = u0; *(float4*)&c8[4] = u1;
        float t = 0.f;
#pragma unroll
        for (int k = 0; k < 8; ++k) t = fmaf(fast_tanhf_(inpr[k] + c8[k]), vr[k], t);
#pragma unroll
        for (int off = 32; off > 0; off >>= 1) t += __shfl_xor(t, off);
        float mn = fmaxf(m, t);
        float sc = __expf(m - mn);
        float p  = __expf(t - mn);
        l = l * sc + p;
#pragma unroll
        for (int k = 0; k < 8; ++k) w[k] = w[k] * sc + p * c8[k];
        m = mn;
    };

    float4 c0 = *reinterpret_cast<const float4*>(sp);
    float4 c1 = *reinterpret_cast<const float4*>(sp + 4);
    for (int si = 0; si < 16; ++si) {
        float4 u0 = c0, u1 = c1;
        if (si < 15) {
            c0 = *reinterpret_cast<const float4*>(sp + (size_t)(si + 1) * H_);
            c1 = *reinterpret_cast<const float4*>(sp + (size_t)(si + 1) * H_ + 4);
        }
        process(u0, u1);
    }

    __shared__ float wl[8 * 512];
    __shared__ float ml[8], ll[8];
#pragma unroll
    for (int k = 0; k < 8; ++k) wl[wv * 512 + lane * 8 + k] = w[k];
    if (lane == 0) { ml[wv] = m; ll[wv] = l; }
    __syncthreads();

    float M = ml[0];
#pragma unroll
    for (int u = 1; u < 8; ++u) M = fmaxf(M, ml[u]);
    float lt = 0.f, wt = 0.f;
#pragma unroll
    for (int u = 0; u < 8; ++u) {
        float e = __expf(ml[u] - M);
        lt += e * ll[u];
        wt += e * wl[u * 512 + tid];
    }
    if (tid == 0) { pm[blk] = M; pl[blk] = lt; }
    pw[(size_t)blk * 512 + tid] = wt;
}

// post-loop: finalize step 63 hidden + copy final c; also write hist[63] hidden.
__global__ __launch_bounds__(256) void k_fin63(const float* __restrict__ Po,
    const float* __restrict__ b_ho, const float* __restrict__ cbuf,
    float* __restrict__ hist63, float* __restrict__ hf, float* __restrict__ cf)
{
    int i = blockIdx.x * blockDim.x + threadIdx.x;
    int b = i >> 9, h = i & 511;
    float v = b_ho[h];
#pragma unroll
    for (int ks = 0; ks < 8; ++ks) v += Po[((size_t)ks * 128 + b) * 512 + h];
    v = tanhf(v);
    hf[i] = v;
    cf[i] = cbuf[i];
    hist63[(size_t)b * 1024 + h] = v;
}

__global__ __launch_bounds__(128) void k_argmax(const float* __restrict__ outp,
                                                float* __restrict__ preds)
{
    int row = blockIdx.x;
    int tid = threadIdx.x;
    float v = outp[(size_t)row * L_ + tid];
    int idx = tid;
#pragma unroll
    for (int off = 32; off > 0; off >>= 1) {
        float ov = __shfl_xor(v, off);
        int oi = __shfl_xor(idx, off);
        if (ov > v || (ov == v && oi < idx)) { v = ov; idx = oi; }
    }
    __shared__ float sv[2];
    __shared__ int si[2];
    if ((tid & 63) == 0) { sv[tid >> 6] = v; si[tid >> 6] = idx; }
    __syncthreads();
    if (tid == 0) {
        float v0 = sv[0], v1 = sv[1];
        int i0 = si[0], i1 = si[1];
        int r = (v1 > v0 || (v1 == v0 && i1 < i0)) ? i1 : i0;
        preds[row] = (float)r;
    }
}

// ---------------------------------------------------------------------------
extern "C" void kernel_launch(void* const* d_in, const int* in_sizes, int n_in,
                              void* d_out, int out_size, void* d_ws, size_t ws_size,
                              hipStream_t stream)
{
    const float* dec_in  = (const float*)d_in[2];
    const float* h0      = (const float*)d_in[3];
    const float* c0      = (const float*)d_in[4];
    const float* context = (const float*)d_in[5];
    const int*   labels  = (const int*)d_in[6];
    const float* emb     = (const float*)d_in[8];
    const float* W_ih    = (const float*)d_in[9];
    const float* b_ih    = (const float*)d_in[10];
    const float* W_hh    = (const float*)d_in[11];
    const float* b_hh    = (const float*)d_in[12];
    const float* W_ho    = (const float*)d_in[13];
    const float* b_ho    = (const float*)d_in[14];
    const float* W_ain   = (const float*)d_in[15];
    const float* b_ain   = (const float*)d_in[16];
    const float* W_actx  = (const float*)d_in[17];
    const float* b_actx  = (const float*)d_in[18];
    const float* Vv      = (const float*)d_in[19];
    const float* W_out   = (const float*)d_in[20];
    const float* b_out   = (const float*)d_in[21];

    float* ws = (float*)d_ws;
    float* X     = ws; ws += (size_t)T_ * B_ * E_;
    float* xproj = ws; ws += (size_t)T_ * B_ * G4H;
    float* xout  = ws; ws += (size_t)T_ * B_ * L_;
    float* ctx   = ws; ws += (size_t)B_ * S_ * H_;          // 67.1M fp32 (exact)
    float* hist  = ws; ws += (size_t)T_ * B_ * 1024;
    float* Wip   = ws; ws += (size_t)G4H * 512;
    float* Whp   = ws; ws += (size_t)G4H * 512;
    float* bp    = ws; ws += G4H;
    float* Pa    = ws; ws += (size_t)8 * B_ * H_;
    float* Po    = ws; ws += (size_t)8 * B_ * H_;
    float* cbuf  = ws; ws += (size_t)B_ * H_;
    float* hbuf  = ws; ws += (size_t)B_ * H_;
    float* hlstm = ws; ws += (size_t)B_ * H_;
    float* pm    = ws; ws += (size_t)B_ * QS;
    float* pl    = ws; ws += (size_t)B_ * QS;
    float* pw    = ws; ws += (size_t)B_ * QS * 512;

    float* out_logits = (float*)d_out;
    float* out_preds  = out_logits + (size_t)B_ * T_ * L_;
    float* out_hf     = out_preds + (size_t)B_ * T_;
    float* out_cf     = out_hf + (size_t)B_ * H_;

    // ---- precompute ----
    k_embed<<<2048, 256, 0, stream>>>(dec_in, labels, emb, X);
    k_init<<<256, 256, 0, stream>>>(h0, c0, hbuf, cbuf);
    k_perm<<<G4H, 128, 0, stream>>>(W_ih, W_hh, b_ih, b_hh, Wip, Whp, bp);
    gemm_split<<<dim3(16, 64), 256, 0, stream>>>(X, E_, Wip, E_, bp, nullptr, 0,
                                                 xproj, G4H, E_, 0, 0);
    gemm_split<<<dim3(1, 64), 256, 0, stream>>>(X, E_, W_out + 1024, 1536, b_out, nullptr, 0,
                                                xout, L_, E_, 0, 0);
    // ctx = context @ W_attn_ctx^T + b_attn_ctx  (fp32-exact)
    gemm_split<<<dim3(4, 1024), 256, 0, stream>>>(context, H_, W_actx, H_, b_actx, nullptr, 0,
                                                  ctx, H_, H_, 0, 0);

    // ---- sequential decode: 4 kernels/step ----
    for (int t = 0; t < T_; ++t) {
        float* hist_t = hist + (size_t)t * B_ * 1024;
        float* hist_prev = hist + (size_t)(t > 0 ? t - 1 : 0) * B_ * 1024;
        k_gateslstm<<<dim3(32, 4), 256, 0, stream>>>(hbuf, Po, b_ho, Whp,
                                                     xproj + (size_t)t * B_ * G4H,
                                                     cbuf, hlstm, hist_prev, t > 0 ? 1 : 0);
        gemm_stepk<<<dim3(8, 8), 256, 0, stream>>>(hlstm, H_, W_ain, H_, Pa, H_, 64);
        k_attn<<<B_ * QS, 512, 0, stream>>>(ctx, Pa, b_ain, Vv, pm, pl, pw);
        k_who<<<dim3(8, 8), 256, 0, stream>>>(pm, pl, pw, hlstm, W_ho, Po, hist_t);
    }

    // ---- post loop: finalize h(63)/c, deferred logits GEMM + argmax ----
    k_fin63<<<256, 256, 0, stream>>>(Po, b_ho, cbuf,
                                     hist + (size_t)63 * B_ * 1024, out_hf, out_cf);
    gemm_split<<<dim3(1, 64), 256, 0, stream>>>(hist, 1024, W_out, 1536, nullptr,
                                                xout, L_, out_logits, L_, 1024, 0, 1);
    k_argmax<<<B_ * T_, 128, 0, stream>>>(out_logits, out_preds);
}